// Round 1
// baseline (119.187 us; speedup 1.0000x reference)
//
#include <hip/hip_runtime.h>
#include <hip/hip_bf16.h>

// Max-unpool 2x2 stride 2, NHWC fp32.
// Input:  inputs  (8,112,112,256) f32, indices (8,112,112,256) i32 in {0..3}
// Output: (8,224,224,256) f32.
// index k -> (di,dj) = (k>>1, k&1); out[n][2h+di][2w+dj][d] = in, others 0.
//
// Strategy: one thread per input float4 (D contiguous). Compute the 4 masked
// output float4s and store all 4 (each store coalesced across the wave since
// the (di,dj) target of each store # is uniform). Every output byte written
// exactly once -> no zero-fill pass, no scatter, no atomics.

#define H_IN 112
#define W_IN 112
#define DVEC 64              // 256 floats / 4
#define W_OUT_VEC (224 * 64) // float4 stride of one output row = 14336

__global__ __launch_bounds__(256) void maxunpool_kernel(
    const float4* __restrict__ in,
    const int4* __restrict__ idx,
    float4* __restrict__ out,
    int nvec)
{
    int stride = gridDim.x * blockDim.x;
    for (int v = blockIdx.x * blockDim.x + threadIdx.x; v < nvec; v += stride) {
        // v = ((n*112 + h)*112 + w)*64 + dvec
        int dvec = v & 63;
        int rest = v >> 6;          // (n*112 + h)*112 + w
        int w    = rest % W_IN;
        int hn   = rest / W_IN;     // n*112 + h
        int h    = hn % H_IN;
        int n    = hn / H_IN;

        float4 val = in[v];
        int4   ix  = idx[v];

        float4 o0, o1, o2, o3;
        o0.x = (ix.x == 0) ? val.x : 0.0f;
        o0.y = (ix.y == 0) ? val.y : 0.0f;
        o0.z = (ix.z == 0) ? val.z : 0.0f;
        o0.w = (ix.w == 0) ? val.w : 0.0f;

        o1.x = (ix.x == 1) ? val.x : 0.0f;
        o1.y = (ix.y == 1) ? val.y : 0.0f;
        o1.z = (ix.z == 1) ? val.z : 0.0f;
        o1.w = (ix.w == 1) ? val.w : 0.0f;

        o2.x = (ix.x == 2) ? val.x : 0.0f;
        o2.y = (ix.y == 2) ? val.y : 0.0f;
        o2.z = (ix.z == 2) ? val.z : 0.0f;
        o2.w = (ix.w == 2) ? val.w : 0.0f;

        o3.x = (ix.x == 3) ? val.x : 0.0f;
        o3.y = (ix.y == 3) ? val.y : 0.0f;
        o3.z = (ix.z == 3) ? val.z : 0.0f;
        o3.w = (ix.w == 3) ? val.w : 0.0f;

        // output float4 base: ((n*224 + 2h)*224 + 2w)*64 + dvec
        int base = ((n * 224 + 2 * h) * 224 + 2 * w) * DVEC + dvec;

        out[base]                  = o0;  // (di=0, dj=0)
        out[base + DVEC]           = o1;  // (di=0, dj=1)
        out[base + W_OUT_VEC]        = o2;  // (di=1, dj=0)
        out[base + W_OUT_VEC + DVEC] = o3;  // (di=1, dj=1)
    }
}

extern "C" void kernel_launch(void* const* d_in, const int* in_sizes, int n_in,
                              void* d_out, int out_size, void* d_ws, size_t ws_size,
                              hipStream_t stream) {
    const float4* in  = (const float4*)d_in[0];
    const int4*   idx = (const int4*)d_in[1];
    float4*       out = (float4*)d_out;

    int nvec = in_sizes[0] / 4;  // 8*112*112*256 / 4 = 6,422,528

    int block = 256;
    int grid  = 2048;  // grid-stride; ~12 iters/thread, fills 256 CUs
    maxunpool_kernel<<<grid, block, 0, stream>>>(in, idx, out, nvec);
}

// Round 2
// 106.292 us; speedup vs baseline: 1.1213x; 1.1213x over previous
//
#include <hip/hip_runtime.h>
#include <hip/hip_bf16.h>

// Max-unpool 2x2 stride 2, NHWC fp32.
// Input:  inputs  (8,112,112,256) f32, indices (8,112,112,256) i32 in {0..3}
// Output: (8,224,224,256) f32.
// index k -> (di,dj) = (k>>1, k&1); out[n][2h+di][2w+dj][d] = in, others 0.
//
// One thread per 2 input float4s (exact-fit grid, no tail). All loads issued
// up front (4 outstanding VMEM/thread). Non-temporal loads/stores: the whole
// 617 MB is a pure stream with zero reuse -> bypass L2 allocation.
// Every output byte written exactly once; all loads/stores coalesced (each
// wave covers one pixel's 256 floats contiguously, dvec = lane).

typedef float f32x4 __attribute__((ext_vector_type(4)));
typedef int   i32x4 __attribute__((ext_vector_type(4)));

#define W_ROW   128      // float4 stride of one 2w step: 2*64
#define H_ROW   28672    // float4 stride of one output row pair start: 224*64*2
#define N_IMG   3211264  // float4 stride of one image: 224*224*64
#define OUT_ROW 14336    // float4 stride of one output row: 224*64

__device__ __forceinline__ void masked4(const f32x4& val, const i32x4& ix, int k, f32x4& o) {
    o[0] = (ix[0] == k) ? val[0] : 0.0f;
    o[1] = (ix[1] == k) ? val[1] : 0.0f;
    o[2] = (ix[2] == k) ? val[2] : 0.0f;
    o[3] = (ix[3] == k) ? val[3] : 0.0f;
}

__device__ __forceinline__ void scatter_one(f32x4* __restrict__ out, int v,
                                            const f32x4& val, const i32x4& ix) {
    int dvec = v & 63;
    int rest = v >> 6;             // (n*112 + h)*112 + w
    int w    = rest % 112;
    int hn   = rest / 112;
    int h    = hn % 112;
    int n    = hn / 112;
    int base = n * N_IMG + h * H_ROW + w * W_ROW + dvec;

    f32x4 o0, o1, o2, o3;
    masked4(val, ix, 0, o0);
    masked4(val, ix, 1, o1);
    masked4(val, ix, 2, o2);
    masked4(val, ix, 3, o3);

    __builtin_nontemporal_store(o0, out + base);                 // (0,0)
    __builtin_nontemporal_store(o1, out + base + 64);            // (0,1)
    __builtin_nontemporal_store(o2, out + base + OUT_ROW);       // (1,0)
    __builtin_nontemporal_store(o3, out + base + OUT_ROW + 64);  // (1,1)
}

__global__ __launch_bounds__(256) void maxunpool_kernel(
    const f32x4* __restrict__ in,
    const i32x4* __restrict__ idx,
    f32x4* __restrict__ out)
{
    int v0 = blockIdx.x * 512 + threadIdx.x;   // first float4
    int v1 = v0 + 256;                         // second float4

    // Issue all 4 loads before any compute (MLP).
    f32x4 val0 = __builtin_nontemporal_load(in + v0);
    i32x4 ix0  = __builtin_nontemporal_load(idx + v0);
    f32x4 val1 = __builtin_nontemporal_load(in + v1);
    i32x4 ix1  = __builtin_nontemporal_load(idx + v1);

    scatter_one(out, v0, val0, ix0);
    scatter_one(out, v1, val1, ix1);
}

extern "C" void kernel_launch(void* const* d_in, const int* in_sizes, int n_in,
                              void* d_out, int out_size, void* d_ws, size_t ws_size,
                              hipStream_t stream) {
    const f32x4* in  = (const f32x4*)d_in[0];
    const i32x4* idx = (const i32x4*)d_in[1];
    f32x4*       out = (f32x4*)d_out;

    // nvec = 8*112*112*64 = 6,422,528 float4s = 12544 blocks * 512 exactly.
    int grid = 12544;
    maxunpool_kernel<<<grid, 256, 0, stream>>>(in, idx, out);
}